// Round 1
// baseline (4330.033 us; speedup 1.0000x reference)
//
#include <hip/hip_runtime.h>

#define NT 256
#define G 4

constexpr int L0 = 360, C1n = 16, L1n = 180, C2n = 32, L2n = 90, C3n = 64, L3n = 45;
constexpr int FCIN = 2880;   // 64*45
constexpr int SD = 67;
constexpr int NQ = 2278;     // 67*68/2
constexpr int LIB = 2480;    // 1 + 67 + 2278 + 67 + 67

__global__ __launch_bounds__(NT) void sindy_fused(
    const float* __restrict__ lidar, const float* __restrict__ odom,
    const float* __restrict__ w1, const float* __restrict__ b1,
    const float* __restrict__ w2, const float* __restrict__ b2,
    const float* __restrict__ w3, const float* __restrict__ b3,
    const float* __restrict__ fcw, const float* __restrict__ fcb,
    const float* __restrict__ sw, float* __restrict__ out, int B)
{
    // transposed weights: [i*5+k][o] so 4-o tiles read as float4 from LDS
    __shared__ float s_w1t[5 * 16];
    __shared__ float s_b1[16];
    __shared__ float s_w2t[80 * 32];
    __shared__ float s_b2[32];
    __shared__ float s_w3t[160 * 64];
    __shared__ float s_b3[64];
    __shared__ float s_x[L0];
    __shared__ float s_c1[C1n * L1n];   // 2880
    __shared__ float s_c2[C2n * L2n];   // 2880
    __shared__ float s_c3[G][FCIN];     // 4*2880
    __shared__ float s_state[G][68];
    __shared__ unsigned short s_qab[NQ];

    const int tid = threadIdx.x;

    // ---- stage weights (transpose into LDS) ----
    for (int idx = tid; idx < 80; idx += NT) { int o = idx / 5, k = idx % 5; s_w1t[k * 16 + o] = w1[idx]; }
    for (int idx = tid; idx < 16; idx += NT) s_b1[idx] = b1[idx];
    for (int idx = tid; idx < 2560; idx += NT) { int o = idx / 80, r = idx % 80; s_w2t[r * 32 + o] = w2[idx]; }
    for (int idx = tid; idx < 32; idx += NT) s_b2[idx] = b2[idx];
    for (int idx = tid; idx < 10240; idx += NT) { int o = idx / 160, r = idx % 160; s_w3t[r * 64 + o] = w3[idx]; }
    for (int idx = tid; idx < 64; idx += NT) s_b3[idx] = b3[idx];

    // ---- triu(67) pair LUT: q -> (a,b) ----
    for (int q = tid; q < NQ; q += NT) {
        float qf = (float)q;
        int a = (int)((135.0f - sqrtf(135.0f * 135.0f - 8.0f * qf)) * 0.5f);
        a = a < 0 ? 0 : (a > 66 ? 66 : a);
        while (a > 0 && (a * 67 - (a * (a - 1)) / 2) > q) --a;
        while (a < 66 && ((a + 1) * 67 - ((a + 1) * a) / 2) <= q) ++a;
        int b = a + (q - (a * 67 - (a * (a - 1)) / 2));
        s_qab[q] = (unsigned short)((a << 8) | b);
    }
    __syncthreads();

    // ---- per-sample conv pipeline ----
    for (int g = 0; g < G; ++g) {
        const int n = blockIdx.x * G + g;
        for (int idx = tid; idx < L0; idx += NT) s_x[idx] = lidar[(long)n * L0 + idx];
        __syncthreads();

        // conv1: 16ch x 180, thread tile 4o x 3t (4 ogroups * 60 tgroups = 240 thr)
        if (tid < 240) {
            int og = tid / 60, tg = tid % 60, o0 = og * 4, t0 = tg * 3;
            float acc[4][3] = {};
            #pragma unroll
            for (int k = 0; k < 5; k++) {
                float4 wv = *(const float4*)&s_w1t[k * 16 + o0];
                float wo[4] = {wv.x, wv.y, wv.z, wv.w};
                #pragma unroll
                for (int tt = 0; tt < 3; tt++) {
                    int u = 2 * (t0 + tt) + k - 2;
                    float xv = (u >= 0 && u < L0) ? s_x[u] : 0.f;
                    #pragma unroll
                    for (int oo = 0; oo < 4; oo++) acc[oo][tt] += wo[oo] * xv;
                }
            }
            #pragma unroll
            for (int oo = 0; oo < 4; oo++) {
                float bb = s_b1[o0 + oo];
                #pragma unroll
                for (int tt = 0; tt < 3; tt++) {
                    float v = acc[oo][tt] + bb;
                    s_c1[(o0 + oo) * L1n + t0 + tt] = v > 0.f ? v : 0.f;
                }
            }
        }
        __syncthreads();

        // conv2: 32ch x 90, thread tile 4o x 3t (8 og * 30 tg = 240 thr)
        if (tid < 240) {
            int og = tid / 30, tg = tid % 30, o0 = og * 4, t0 = tg * 3;
            float acc[4][3] = {};
            for (int i = 0; i < 16; i++) {
                float xin[9];
                #pragma unroll
                for (int r = 0; r < 9; r++) {
                    int u = 2 * t0 - 2 + r;
                    xin[r] = (u >= 0 && u < L1n) ? s_c1[i * L1n + u] : 0.f;
                }
                #pragma unroll
                for (int k = 0; k < 5; k++) {
                    float4 wv = *(const float4*)&s_w2t[(i * 5 + k) * 32 + o0];
                    float wo[4] = {wv.x, wv.y, wv.z, wv.w};
                    #pragma unroll
                    for (int tt = 0; tt < 3; tt++) {
                        float xv = xin[2 * tt + k];
                        #pragma unroll
                        for (int oo = 0; oo < 4; oo++) acc[oo][tt] += wo[oo] * xv;
                    }
                }
            }
            #pragma unroll
            for (int oo = 0; oo < 4; oo++) {
                float bb = s_b2[o0 + oo];
                #pragma unroll
                for (int tt = 0; tt < 3; tt++) {
                    float v = acc[oo][tt] + bb;
                    s_c2[(o0 + oo) * L2n + t0 + tt] = v > 0.f ? v : 0.f;
                }
            }
        }
        __syncthreads();

        // conv3: 64ch x 45, thread tile 4o x 3t (16 og * 15 tg = 240 thr)
        if (tid < 240) {
            int og = tid / 15, tg = tid % 15, o0 = og * 4, t0 = tg * 3;
            float acc[4][3] = {};
            for (int i = 0; i < 32; i++) {
                float xin[9];
                #pragma unroll
                for (int r = 0; r < 9; r++) {
                    int u = 2 * t0 - 2 + r;
                    xin[r] = (u >= 0 && u < L2n) ? s_c2[i * L2n + u] : 0.f;
                }
                #pragma unroll
                for (int k = 0; k < 5; k++) {
                    float4 wv = *(const float4*)&s_w3t[(i * 5 + k) * 64 + o0];
                    float wo[4] = {wv.x, wv.y, wv.z, wv.w};
                    #pragma unroll
                    for (int tt = 0; tt < 3; tt++) {
                        float xv = xin[2 * tt + k];
                        #pragma unroll
                        for (int oo = 0; oo < 4; oo++) acc[oo][tt] += wo[oo] * xv;
                    }
                }
            }
            #pragma unroll
            for (int oo = 0; oo < 4; oo++) {
                float bb = s_b3[o0 + oo];
                #pragma unroll
                for (int tt = 0; tt < 3; tt++) {
                    float v = acc[oo][tt] + bb;
                    s_c3[g][(o0 + oo) * L3n + t0 + tt] = v > 0.f ? v : 0.f;  // m = o*45+t matches reshape
                }
            }
        }
        __syncthreads();
    }

    // ---- fc: thread = (g, j), contiguous float4 row reads ----
    {
        int g = tid >> 6, j = tid & 63;
        const float* wrow = fcw + j * FCIN;
        const float* c3p = s_c3[g];
        float acc = 0.f;
        #pragma unroll 8
        for (int m = 0; m < FCIN; m += 4) {
            float4 wv = *(const float4*)&wrow[m];
            float4 xv = *(const float4*)&c3p[m];
            acc += wv.x * xv.x + wv.y * xv.y + wv.z * xv.z + wv.w * xv.w;
        }
        s_state[g][j] = acc + fcb[j];
        if (tid < G * 3) {
            int gg = tid / 3, jj = tid % 3;
            s_state[gg][64 + jj] = odom[(long)(blockIdx.x * G + gg) * 3 + jj];
        }
    }
    __syncthreads();

    // ---- SINDy tail: one wave per sample ----
    {
        int g = tid >> 6, lane = tid & 63;
        const int n = blockIdx.x * G + g;
        const float* st = s_state[g];
        const float* w0 = sw;
        const float* w1s = sw + LIB;
        const float* w2s = sw + 2 * LIB;
        float a0 = 0.f, a1 = 0.f, a2 = 0.f;
        for (int i = lane; i < SD; i += 64) {
            float s = st[i], sn = sinf(s), cs = cosf(s);
            a0 += w0[1 + i] * s + w0[2346 + i] * sn + w0[2413 + i] * cs;
            a1 += w1s[1 + i] * s + w1s[2346 + i] * sn + w1s[2413 + i] * cs;
            a2 += w2s[1 + i] * s + w2s[2346 + i] * sn + w2s[2413 + i] * cs;
        }
        if (lane == 0) { a0 += w0[0]; a1 += w1s[0]; a2 += w2s[0]; }
        for (int q = lane; q < NQ; q += 64) {
            int ab = s_qab[q];
            float p = st[ab >> 8] * st[ab & 255];
            a0 += w0[68 + q] * p; a1 += w1s[68 + q] * p; a2 += w2s[68 + q] * p;
        }
        #pragma unroll
        for (int off = 32; off; off >>= 1) {
            a0 += __shfl_xor(a0, off, 64);
            a1 += __shfl_xor(a1, off, 64);
            a2 += __shfl_xor(a2, off, 64);
        }
        if (lane == 0) {
            out[(long)n * 3 + 0] = odom[(long)n * 3 + 0] + 0.1f * a0;
            out[(long)n * 3 + 1] = odom[(long)n * 3 + 1] + 0.1f * a1;
            out[(long)n * 3 + 2] = odom[(long)n * 3 + 2] + 0.1f * a2;
        }
    }
}

extern "C" void kernel_launch(void* const* d_in, const int* in_sizes, int n_in,
                              void* d_out, int out_size, void* d_ws, size_t ws_size,
                              hipStream_t stream) {
    const float* lidar = (const float*)d_in[0];
    const float* odom  = (const float*)d_in[1];
    const float* w1    = (const float*)d_in[2];
    const float* b1    = (const float*)d_in[3];
    const float* w2    = (const float*)d_in[4];
    const float* b2    = (const float*)d_in[5];
    const float* w3    = (const float*)d_in[6];
    const float* b3    = (const float*)d_in[7];
    const float* fcw   = (const float*)d_in[8];
    const float* fcb   = (const float*)d_in[9];
    const float* sw    = (const float*)d_in[10];
    float* out = (float*)d_out;

    int B = in_sizes[0] / L0;          // 32768
    int blocks = B / G;                // 8192 (B divisible by 4)
    sindy_fused<<<blocks, NT, 0, stream>>>(lidar, odom, w1, b1, w2, b2, w3, b3,
                                           fcw, fcb, sw, out, B);
}

// Round 2
// 811.507 us; speedup vs baseline: 5.3358x; 5.3358x over previous
//
#include <hip/hip_runtime.h>
#include <hip/hip_bf16.h>

typedef __attribute__((ext_vector_type(8))) short bf16x8;
typedef __attribute__((ext_vector_type(4))) short short4v;
typedef __attribute__((ext_vector_type(4))) float f32x4;

#define NT 256
#define NS 8

constexpr int L0 = 360, L2n = 90, L3n = 45;
constexpr int SD = 67, NQ = 2278, LIB = 2480, FCIN = 2880;

// c1: [NS][188 rows][20 ch] bf16 ; row = conv1 position + 4 (zero borders)
constexpr int C1_CH = 20, S1B = 188 * C1_CH * 2;          // 7520 B / sample
// c2: [NS][96 rows][44 ch] bf16 ; row = conv2 position + 4
constexpr int C2_CH = 44, S2B = 96 * C2_CH * 2;           // 8448 B / sample
// c3: [NS][2888] bf16 (aliases c1), m' = t*64+o, XOR-bit4 swizzled
constexpr int S3B = 2888 * 2;                             // 5776 B / sample

constexpr int OFF_C1 = 0;
constexpr int SZ_C1 = NS * S1B;                 // 60160
constexpr int OFF_C2 = OFF_C1 + SZ_C1;          // 60160
constexpr int SZ_C2 = NS * S2B + 512;           // 68096 (pad for cross-sample garbage reads)
constexpr int OFF_LID = OFF_C2;                 // lidar f32 stage aliases c2
constexpr int OFF_W2F = OFF_C2 + SZ_C2;         // 128256 ; [3 pairs][32 o][32 k] bf16
constexpr int OFF_W3F = OFF_W2F + 3 * 32 * 32 * 2;   // 134400 ; [5 kk][64 o][32 i] bf16
constexpr int OFF_W1  = OFF_W3F + 5 * 64 * 32 * 2;   // 154880 ; 80 f32
constexpr int OFF_B1  = OFF_W1 + 320;
constexpr int OFF_B2  = OFF_B1 + 64;
constexpr int OFF_B3  = OFF_B2 + 128;
constexpr int OFF_FCB = OFF_B3 + 256;
constexpr int OFF_QAB = OFF_FCB + 256;          // 2278 u16
constexpr int OFF_STATE = OFF_QAB + 4560;       // [8][68] f32
constexpr int SMEM_BYTES = OFF_STATE + NS * 68 * 4;   // 162640
static_assert(SMEM_BYTES <= 163840, "LDS over budget");

__device__ __forceinline__ short f2b(float f) {
    return (short)__builtin_bit_cast(unsigned short, __float2bfloat16(f));
}
__device__ __forceinline__ bf16x8 ld_frag8(const char* p) {   // 8B-aligned, 2x ds_read_b64
    union { bf16x8 v; short4v h[2]; } u;
    u.h[0] = *(const short4v*)(p);
    u.h[1] = *(const short4v*)(p + 8);
    return u.v;
}

__global__ __launch_bounds__(NT, 1) void sindy_mfma(
    const float* __restrict__ lidar, const float* __restrict__ odom,
    const float* __restrict__ w1, const float* __restrict__ b1,
    const float* __restrict__ w2, const float* __restrict__ b2,
    const float* __restrict__ w3, const float* __restrict__ b3,
    const float* __restrict__ fcw, const float* __restrict__ fcb,
    const float* __restrict__ sw, const short* __restrict__ fcwb,
    float* __restrict__ out)
{
    __shared__ char smem[SMEM_BYTES];
    const int tid = threadIdx.x;
    const int wv = tid >> 6, lane = tid & 63;
    const int lr = lane & 15, lg = lane >> 4;

    // ---------------- P0: zero c1, stage lidar/weights/LUT ----------------
    for (int i = tid; i < SZ_C1 / 4; i += NT) ((int*)(smem + OFF_C1))[i] = 0;
    {
        float* lid = (float*)(smem + OFF_LID);
        const float* gsrc = lidar + (long)blockIdx.x * NS * L0;
        for (int i = tid; i < NS * L0; i += NT) lid[i] = gsrc[i];
    }
    for (int i = tid; i < 80; i += NT) ((float*)(smem + OFF_W1))[i] = w1[i];
    if (tid < 16) ((float*)(smem + OFF_B1))[tid] = b1[tid];
    else if (tid >= 32 && tid < 64) ((float*)(smem + OFF_B2))[tid - 32] = b2[tid - 32];
    else if (tid >= 64 && tid < 128) ((float*)(smem + OFF_B3))[tid - 64] = b3[tid - 64];
    else if (tid >= 128 && tid < 192) ((float*)(smem + OFF_FCB))[tid - 128] = fcb[tid - 128];
    {
        short* w2f = (short*)(smem + OFF_W2F);
        for (int idx = tid; idx < 3 * 32 * 32; idx += NT) {
            int p = idx >> 10, o = (idx >> 5) & 31, k32 = idx & 31;
            int kk = 2 * p + (k32 >> 4), ic = k32 & 15;
            float v = (kk < 5) ? w2[(o * 16 + ic) * 5 + kk] : 0.f;
            w2f[idx] = f2b(v);
        }
        short* w3f = (short*)(smem + OFF_W3F);
        for (int idx = tid; idx < 5 * 64 * 32; idx += NT) {
            int kk = idx >> 11, o = (idx >> 5) & 63, ic = idx & 31;
            w3f[idx] = f2b(w3[(o * 32 + ic) * 5 + kk]);
        }
        unsigned short* qab = (unsigned short*)(smem + OFF_QAB);
        for (int q = tid; q < NQ; q += NT) {
            float qf = (float)q;
            int a = (int)((135.0f - sqrtf(135.0f * 135.0f - 8.0f * qf)) * 0.5f);
            a = a < 0 ? 0 : (a > 66 ? 66 : a);
            while (a > 0 && (a * 67 - (a * (a - 1)) / 2) > q) --a;
            while (a < 66 && ((a + 1) * 67 - ((a + 1) * a) / 2) <= q) ++a;
            int b = a + (q - (a * 67 - (a * (a - 1)) / 2));
            qab[q] = (unsigned short)((a << 8) | b);
        }
    }
    __syncthreads();

    // ---------------- P1: conv1 on VALU fp32 -> c1 bf16 ----------------
    {
        int s = tid >> 5, rem = tid & 31, op = rem >> 2, tc = rem & 3;
        int o0 = op * 2;
        const float* lw = (const float*)(smem + OFF_W1);
        float wA[5], wB[5];
        #pragma unroll
        for (int k = 0; k < 5; k++) { wA[k] = lw[o0 * 5 + k]; wB[k] = lw[(o0 + 1) * 5 + k]; }
        float bA = ((const float*)(smem + OFF_B1))[o0];
        float bB = ((const float*)(smem + OFF_B1))[o0 + 1];
        const float* xs = (const float*)(smem + OFF_LID) + s * L0;
        char* c1s = smem + OFF_C1 + s * S1B;
        for (int t = tc * 45; t < tc * 45 + 45; ++t) {
            float a0 = bA, a1 = bB;
            #pragma unroll
            for (int k = 0; k < 5; k++) {
                int u = 2 * t + k - 2;
                float x = (u >= 0 && u < L0) ? xs[u] : 0.f;
                a0 += wA[k] * x; a1 += wB[k] * x;
            }
            a0 = fmaxf(a0, 0.f); a1 = fmaxf(a1, 0.f);
            int pk = (int)(unsigned short)f2b(a0) | ((int)(unsigned short)f2b(a1) << 16);
            *(int*)(c1s + (t + 4) * (C1_CH * 2) + o0 * 2) = pk;
        }
    }
    __syncthreads();

    // ---------------- P2a: zero c2 (lidar alias now dead) ----------------
    for (int i = tid; i < SZ_C2 / 4; i += NT) ((int*)(smem + OFF_C2))[i] = 0;
    __syncthreads();

    // ---------------- P2b: conv2 via MFMA (A=w2 tiles, B=c1 acts, D=[o][t]) ----------------
    {
        const int ot = wv & 1, sb = (wv >> 1) * 4;
        const int o0 = ot * 16;
        bf16x8 af[3];
        #pragma unroll
        for (int p = 0; p < 3; p++)
            af[p] = *(const bf16x8*)(smem + OFF_W2F + ((p * 32 + o0 + lr) * 32 + lg * 8) * 2);
        const int orow = o0 + lg * 4;
        float bia[4];
        #pragma unroll
        for (int r = 0; r < 4; r++) bia[r] = ((const float*)(smem + OFF_B2))[orow + r];
        const int kkp = lane >> 5, i0 = (lg & 1) * 8;
        for (int idx = 0; idx < 24; ++idx) {
            const int s = sb + idx / 6, t0 = (idx % 6) * 16;
            const char* base = smem + OFF_C1 + s * S1B;
            f32x4 acc = {0.f, 0.f, 0.f, 0.f};
            #pragma unroll
            for (int p = 0; p < 3; p++) {
                int row = 2 * t0 + 2 * lr + 2 * p + kkp + 2;
                bf16x8 bf = ld_frag8(base + row * (C1_CH * 2) + i0 * 2);
                acc = __builtin_amdgcn_mfma_f32_16x16x32_bf16(af[p], bf, acc, 0, 0, 0);
            }
            const int tw = t0 + lr;
            if (tw < L2n) {
                short4v pk = { f2b(fmaxf(acc[0] + bia[0], 0.f)), f2b(fmaxf(acc[1] + bia[1], 0.f)),
                               f2b(fmaxf(acc[2] + bia[2], 0.f)), f2b(fmaxf(acc[3] + bia[3], 0.f)) };
                *(short4v*)(smem + OFF_C2 + s * S2B + (tw + 4) * (C2_CH * 2) + orow * 2) = pk;
            }
        }
    }
    __syncthreads();

    // ---------------- P3: conv3 via MFMA -> c3 (swizzled, aliases c1) ----------------
    {
        const int o0 = wv * 16;
        bf16x8 af[5];
        #pragma unroll
        for (int kk = 0; kk < 5; kk++)
            af[kk] = *(const bf16x8*)(smem + OFF_W3F + ((kk * 64 + o0 + lr) * 32 + lg * 8) * 2);
        const int orow = o0 + lg * 4;
        float bia[4];
        #pragma unroll
        for (int r = 0; r < 4; r++) bia[r] = ((const float*)(smem + OFF_B3))[orow + r];
        const int i0 = lg * 8;
        for (int idx = 0; idx < 24; ++idx) {
            const int s = idx / 3, t0 = (idx % 3) * 16;
            const char* base = smem + OFF_C2 + s * S2B;
            f32x4 acc = {0.f, 0.f, 0.f, 0.f};
            #pragma unroll
            for (int kk = 0; kk < 5; kk++) {
                int row = 2 * t0 + 2 * lr + kk + 2;
                bf16x8 bf = ld_frag8(base + row * (C2_CH * 2) + i0 * 2);
                acc = __builtin_amdgcn_mfma_f32_16x16x32_bf16(af[kk], bf, acc, 0, 0, 0);
            }
            const int tw = t0 + lr;
            if (tw < L3n) {
                short4v pk = { f2b(fmaxf(acc[0] + bia[0], 0.f)), f2b(fmaxf(acc[1] + bia[1], 0.f)),
                               f2b(fmaxf(acc[2] + bia[2], 0.f)), f2b(fmaxf(acc[3] + bia[3], 0.f)) };
                int byteoff = (tw * 64 + orow) * 2;
                byteoff ^= (tw & 7) << 4;
                *(short4v*)(smem + OFF_C1 + s * S3B + byteoff) = pk;
            }
        }
    }
    __syncthreads();

    // ---------------- P4: fc via MFMA (M=8 samples, N=64, K=2880) ----------------
    {
        const int j0 = wv * 16;
        f32x4 acc0 = {0.f, 0.f, 0.f, 0.f}, acc1 = {0.f, 0.f, 0.f, 0.f};
        for (int kt = 0; kt < 90; kt += 2) {
            {
                int k = kt * 32 + lg * 8;
                int bo = (k * 2) ^ (((k >> 6) & 7) << 4);
                bf16x8 av = *(const bf16x8*)(smem + OFF_C1 + lr * S3B + bo);
                bf16x8 bv;
                if (fcwb) bv = *(const bf16x8*)(fcwb + (long)(j0 + lr) * FCIN + k);
                else {
                    #pragma unroll
                    for (int e = 0; e < 8; e++) {
                        int mp = k + e, o = mp & 63, t = mp >> 6;
                        bv[e] = f2b(fcw[(long)(j0 + lr) * FCIN + o * 45 + t]);
                    }
                }
                acc0 = __builtin_amdgcn_mfma_f32_16x16x32_bf16(av, bv, acc0, 0, 0, 0);
            }
            {
                int k = (kt + 1) * 32 + lg * 8;
                int bo = (k * 2) ^ (((k >> 6) & 7) << 4);
                bf16x8 av = *(const bf16x8*)(smem + OFF_C1 + lr * S3B + bo);
                bf16x8 bv;
                if (fcwb) bv = *(const bf16x8*)(fcwb + (long)(j0 + lr) * FCIN + k);
                else {
                    #pragma unroll
                    for (int e = 0; e < 8; e++) {
                        int mp = k + e, o = mp & 63, t = mp >> 6;
                        bv[e] = f2b(fcw[(long)(j0 + lr) * FCIN + o * 45 + t]);
                    }
                }
                acc1 = __builtin_amdgcn_mfma_f32_16x16x32_bf16(av, bv, acc1, 0, 0, 0);
            }
        }
        if (lg < 2) {
            float* st = (float*)(smem + OFF_STATE);
            float fb = ((const float*)(smem + OFF_FCB))[j0 + lr];
            #pragma unroll
            for (int r = 0; r < 4; r++) {
                int s = lg * 4 + r;
                st[s * 68 + j0 + lr] = acc0[r] + acc1[r] + fb;
            }
        }
        if (tid < NS * 3) {
            int s = tid / 3, jj = tid % 3;
            ((float*)(smem + OFF_STATE))[s * 68 + 64 + jj] = odom[((long)blockIdx.x * NS + s) * 3 + jj];
        }
    }
    __syncthreads();

    // ---------------- P5: SINDy tail fp32 (one wave / 2 samples) ----------------
    {
        const float* stb = (const float*)(smem + OFF_STATE);
        const unsigned short* qab = (const unsigned short*)(smem + OFF_QAB);
        for (int ss = 0; ss < 2; ++ss) {
            const int s = wv * 2 + ss;
            const long n = (long)blockIdx.x * NS + s;
            const float* st = stb + s * 68;
            float a0 = 0.f, a1 = 0.f, a2 = 0.f;
            for (int i = lane; i < SD; i += 64) {
                float sv = st[i], sn = sinf(sv), cs = cosf(sv);
                a0 += sw[1 + i] * sv + sw[2346 + i] * sn + sw[2413 + i] * cs;
                a1 += sw[LIB + 1 + i] * sv + sw[LIB + 2346 + i] * sn + sw[LIB + 2413 + i] * cs;
                a2 += sw[2 * LIB + 1 + i] * sv + sw[2 * LIB + 2346 + i] * sn + sw[2 * LIB + 2413 + i] * cs;
            }
            if (lane == 0) { a0 += sw[0]; a1 += sw[LIB]; a2 += sw[2 * LIB]; }
            for (int q = lane; q < NQ; q += 64) {
                int ab = qab[q];
                float p = st[ab >> 8] * st[ab & 255];
                a0 += sw[68 + q] * p; a1 += sw[LIB + 68 + q] * p; a2 += sw[2 * LIB + 68 + q] * p;
            }
            #pragma unroll
            for (int off = 32; off; off >>= 1) {
                a0 += __shfl_xor(a0, off, 64);
                a1 += __shfl_xor(a1, off, 64);
                a2 += __shfl_xor(a2, off, 64);
            }
            if (lane == 0) {
                out[n * 3 + 0] = odom[n * 3 + 0] + 0.1f * a0;
                out[n * 3 + 1] = odom[n * 3 + 1] + 0.1f * a1;
                out[n * 3 + 2] = odom[n * 3 + 2] + 0.1f * a2;
            }
        }
    }
}

// pre-kernel: fcw f32 [j][o*45+t] -> bf16 [j][t*64+o] in workspace
__global__ __launch_bounds__(256) void fcw_convert(const float* __restrict__ fcw,
                                                   short* __restrict__ fcwb) {
    int idx = blockIdx.x * 256 + threadIdx.x;
    if (idx >= 64 * FCIN) return;
    int j = idx / FCIN, mp = idx % FCIN;
    int o = mp & 63, t = mp >> 6;
    fcwb[idx] = f2b(fcw[j * FCIN + o * 45 + t]);
}

extern "C" void kernel_launch(void* const* d_in, const int* in_sizes, int n_in,
                              void* d_out, int out_size, void* d_ws, size_t ws_size,
                              hipStream_t stream) {
    const float* lidar = (const float*)d_in[0];
    const float* odom  = (const float*)d_in[1];
    const float* w1    = (const float*)d_in[2];
    const float* b1    = (const float*)d_in[3];
    const float* w2    = (const float*)d_in[4];
    const float* b2    = (const float*)d_in[5];
    const float* w3    = (const float*)d_in[6];
    const float* b3    = (const float*)d_in[7];
    const float* fcw   = (const float*)d_in[8];
    const float* fcb   = (const float*)d_in[9];
    const float* sw    = (const float*)d_in[10];
    float* out = (float*)d_out;

    int B = in_sizes[0] / L0;          // 32768
    int blocks = B / NS;               // 4096

    short* fcwb = nullptr;
    if (ws_size >= (size_t)(64 * FCIN * 2)) {
        fcwb = (short*)d_ws;
        fcw_convert<<<(64 * FCIN + 255) / 256, 256, 0, stream>>>(fcw, fcwb);
    }
    sindy_mfma<<<blocks, NT, 0, stream>>>(lidar, odom, w1, b1, w2, b2, w3, b3,
                                          fcw, fcb, sw, fcwb, out);
}

// Round 3
// 671.405 us; speedup vs baseline: 6.4492x; 1.2087x over previous
//
#include <hip/hip_runtime.h>
#include <hip/hip_bf16.h>

typedef __attribute__((ext_vector_type(8))) short bf16x8;
typedef __attribute__((ext_vector_type(4))) short short4v;
typedef __attribute__((ext_vector_type(4))) float f32x4;
typedef __attribute__((ext_vector_type(4))) float float4v;

#define NT 256
#define NS 4

constexpr int L0 = 360, L2n = 90, L3n = 45;
constexpr int SD = 67, NQ = 2278, LIB = 2480, FCIN = 2880;

// c1: [NS][188 rows][20 ch] bf16 ; row = conv1 position + 4 (zero borders)
constexpr int C1_CH = 20, S1B = 188 * C1_CH * 2;          // 7520 B / sample
// c2: [NS][96 rows][44 ch] bf16 ; row = conv2 position + 4
constexpr int C2_CH = 44, S2B = 96 * C2_CH * 2;           // 8448 B / sample
// c3: [NS][2888] bf16 (aliases c1), m' = t*64+o, XOR-bit4 swizzled
constexpr int S3B = 2888 * 2;                             // 5776 B / sample

constexpr int OFF_C1 = 0;
constexpr int SZ_C1 = NS * S1B;                 // 30080
constexpr int OFF_C2 = OFF_C1 + SZ_C1;
constexpr int SZ_C2 = NS * S2B + 512;           // 34304 (pad for tail garbage reads)
constexpr int OFF_LID = OFF_C2;                 // lidar f32 stage aliases c2
constexpr int OFF_W1  = OFF_C2 + SZ_C2;         // 80 f32
constexpr int OFF_B1  = OFF_W1 + 320;
constexpr int OFF_B2  = OFF_B1 + 64;
constexpr int OFF_B3  = OFF_B2 + 128;
constexpr int OFF_FCB = OFF_B3 + 256;
constexpr int OFF_STATE = OFF_FCB + 256;        // [NS][68] f32
constexpr int SMEM_BYTES = OFF_STATE + NS * 68 * 4;   // ~66.5 KB
static_assert(SMEM_BYTES <= 80 * 1024, "need 2 blocks/CU");

// workspace layout (bytes)
constexpr size_t WSO_FCW = 0;                          // [64][2880] bf16, m'=t*64+o
constexpr size_t WSO_W2F = WSO_FCW + 64 * FCIN * 2;    // [3][32][32] bf16
constexpr size_t WSO_W3F = WSO_W2F + 3 * 32 * 32 * 2;  // [5][64][32] bf16
constexpr size_t WSO_QAB = WSO_W3F + 5 * 64 * 32 * 2;  // [2278] u16
constexpr size_t WS_NEED = WSO_QAB + NQ * 2;

__device__ __forceinline__ short f2b(float f) {
    return (short)__builtin_bit_cast(unsigned short, __float2bfloat16(f));
}
__device__ __forceinline__ bf16x8 ld_frag8(const char* p) {   // 8B-aligned LDS, 2x ds_read_b64
    union { bf16x8 v; short4v h[2]; } u;
    u.h[0] = *(const short4v*)(p);
    u.h[1] = *(const short4v*)(p + 8);
    return u.v;
}
__device__ __forceinline__ int2 qab_of(int q) {
    float qf = (float)q;
    int a = (int)((135.0f - sqrtf(135.0f * 135.0f - 8.0f * qf)) * 0.5f);
    a = a < 0 ? 0 : (a > 66 ? 66 : a);
    while (a > 0 && (a * 67 - (a * (a - 1)) / 2) > q) --a;
    while (a < 66 && ((a + 1) * 67 - ((a + 1) * a) / 2) <= q) ++a;
    int b = a + (q - (a * 67 - (a * (a - 1)) / 2));
    return make_int2(a, b);
}

// pre-kernel: convert/permute all weights to bf16 in ws + triu LUT
__global__ __launch_bounds__(256) void pre_convert(
    const float* __restrict__ fcw, const float* __restrict__ w2,
    const float* __restrict__ w3, char* __restrict__ ws) {
    int idx = blockIdx.x * 256 + threadIdx.x;
    if (idx < 64 * FCIN) {
        int j = idx / FCIN, mp = idx % FCIN;
        int o = mp & 63, t = mp >> 6;
        ((short*)(ws + WSO_FCW))[idx] = f2b(fcw[j * FCIN + o * 45 + t]);
    }
    if (idx < 3 * 32 * 32) {
        int p = idx >> 10, o = (idx >> 5) & 31, k32 = idx & 31;
        int kk = 2 * p + (k32 >> 4), ic = k32 & 15;
        float v = (kk < 5) ? w2[(o * 16 + ic) * 5 + kk] : 0.f;
        ((short*)(ws + WSO_W2F))[idx] = f2b(v);
    }
    if (idx < 5 * 64 * 32) {
        int kk = idx >> 11, o = (idx >> 5) & 63, ic = idx & 31;
        ((short*)(ws + WSO_W3F))[idx] = f2b(w3[(o * 32 + ic) * 5 + kk]);
    }
    if (idx < NQ) {
        int2 ab = qab_of(idx);
        ((unsigned short*)(ws + WSO_QAB))[idx] = (unsigned short)((ab.x << 8) | ab.y);
    }
}

__global__ __launch_bounds__(NT, 2) void sindy_mfma(
    const float* __restrict__ lidar, const float* __restrict__ odom,
    const float* __restrict__ w1, const float* __restrict__ b1,
    const float* __restrict__ w2, const float* __restrict__ b2,
    const float* __restrict__ w3, const float* __restrict__ b3,
    const float* __restrict__ fcw, const float* __restrict__ fcb,
    const float* __restrict__ sw, const char* __restrict__ ws,
    float* __restrict__ out)
{
    __shared__ char smem[SMEM_BYTES];
    const int tid = threadIdx.x;
    const int wv = tid >> 6, lane = tid & 63;
    const int lr = lane & 15, lg = lane >> 4;

    // ---------------- P0: zero c1, stage lidar + small params ----------------
    for (int i = tid; i < SZ_C1 / 4; i += NT) ((int*)(smem + OFF_C1))[i] = 0;
    {
        const float4v* gsrc = (const float4v*)(lidar + (long)blockIdx.x * NS * L0);
        float4v* lid = (float4v*)(smem + OFF_LID);
        for (int i = tid; i < NS * L0 / 4; i += NT) lid[i] = gsrc[i];
    }
    for (int i = tid; i < 80; i += NT) ((float*)(smem + OFF_W1))[i] = w1[i];
    if (tid < 16) ((float*)(smem + OFF_B1))[tid] = b1[tid];
    else if (tid >= 32 && tid < 64) ((float*)(smem + OFF_B2))[tid - 32] = b2[tid - 32];
    else if (tid >= 64 && tid < 128) ((float*)(smem + OFF_B3))[tid - 64] = b3[tid - 64];
    else if (tid >= 128 && tid < 192) ((float*)(smem + OFF_FCB))[tid - 128] = fcb[tid - 128];
    __syncthreads();

    // ---------------- P1: conv1 on VALU fp32 -> c1 bf16 ----------------
    {
        int s = tid >> 6, op = lane >> 3, tc = lane & 7;
        int o0 = op * 2;
        const float* lw = (const float*)(smem + OFF_W1);
        float wA[5], wB[5];
        #pragma unroll
        for (int k = 0; k < 5; k++) { wA[k] = lw[o0 * 5 + k]; wB[k] = lw[(o0 + 1) * 5 + k]; }
        float bA = ((const float*)(smem + OFF_B1))[o0];
        float bB = ((const float*)(smem + OFF_B1))[o0 + 1];
        const float* xs = (const float*)(smem + OFF_LID) + s * L0;
        char* c1s = smem + OFF_C1 + s * S1B;
        int tend = tc * 23 + 23; if (tend > 180) tend = 180;
        for (int t = tc * 23; t < tend; ++t) {
            float a0 = bA, a1 = bB;
            #pragma unroll
            for (int k = 0; k < 5; k++) {
                int u = 2 * t + k - 2;
                float x = (u >= 0 && u < L0) ? xs[u] : 0.f;
                a0 += wA[k] * x; a1 += wB[k] * x;
            }
            a0 = fmaxf(a0, 0.f); a1 = fmaxf(a1, 0.f);
            int pk = (int)(unsigned short)f2b(a0) | ((int)(unsigned short)f2b(a1) << 16);
            *(int*)(c1s + (t + 4) * (C1_CH * 2) + o0 * 2) = pk;
        }
    }
    __syncthreads();

    // ---------------- P2a: zero c2 (lidar alias now dead) ----------------
    for (int i = tid; i < SZ_C2 / 4; i += NT) ((int*)(smem + OFF_C2))[i] = 0;
    __syncthreads();

    // ---------------- P2b: conv2 via MFMA (A=w2 tiles, B=c1 acts, D=[o][t]) ----------------
    {
        const int ot = wv & 1, o0 = ot * 16;
        bf16x8 af[3];
        if (ws) {
            #pragma unroll
            for (int p = 0; p < 3; p++)
                af[p] = *(const bf16x8*)(ws + WSO_W2F + ((p * 32 + o0 + lr) * 32 + lg * 8) * 2);
        } else {
            #pragma unroll
            for (int p = 0; p < 3; p++)
                #pragma unroll
                for (int e = 0; e < 8; e++) {
                    int k32 = lg * 8 + e, kk = 2 * p + (k32 >> 4), ic = k32 & 15;
                    af[p][e] = (kk < 5) ? f2b(w2[((o0 + lr) * 16 + ic) * 5 + kk]) : (short)0;
                }
        }
        const int orow = o0 + lg * 4;
        float bia[4];
        #pragma unroll
        for (int r = 0; r < 4; r++) bia[r] = ((const float*)(smem + OFF_B2))[orow + r];
        const int kkp = lane >> 5, i0 = (lg & 1) * 8;
        for (int idx = 0; idx < 12; ++idx) {
            const int s = (wv >> 1) * 2 + idx / 6, t0 = (idx % 6) * 16;
            const char* base = smem + OFF_C1 + s * S1B;
            f32x4 acc = {0.f, 0.f, 0.f, 0.f};
            #pragma unroll
            for (int p = 0; p < 3; p++) {
                int row = 2 * t0 + 2 * lr + 2 * p + kkp + 2;
                bf16x8 bf = ld_frag8(base + row * (C1_CH * 2) + i0 * 2);
                acc = __builtin_amdgcn_mfma_f32_16x16x32_bf16(af[p], bf, acc, 0, 0, 0);
            }
            const int tw = t0 + lr;
            if (tw < L2n) {
                short4v pk = { f2b(fmaxf(acc[0] + bia[0], 0.f)), f2b(fmaxf(acc[1] + bia[1], 0.f)),
                               f2b(fmaxf(acc[2] + bia[2], 0.f)), f2b(fmaxf(acc[3] + bia[3], 0.f)) };
                *(short4v*)(smem + OFF_C2 + s * S2B + (tw + 4) * (C2_CH * 2) + orow * 2) = pk;
            }
        }
    }
    __syncthreads();

    // ---------------- P3: conv3 via MFMA -> c3 (swizzled, aliases c1) ----------------
    {
        const int o0 = wv * 16;
        bf16x8 af[5];
        if (ws) {
            #pragma unroll
            for (int kk = 0; kk < 5; kk++)
                af[kk] = *(const bf16x8*)(ws + WSO_W3F + ((kk * 64 + o0 + lr) * 32 + lg * 8) * 2);
        } else {
            #pragma unroll
            for (int kk = 0; kk < 5; kk++)
                #pragma unroll
                for (int e = 0; e < 8; e++)
                    af[kk][e] = f2b(w3[((o0 + lr) * 32 + lg * 8 + e) * 5 + kk]);
        }
        const int orow = o0 + lg * 4;
        float bia[4];
        #pragma unroll
        for (int r = 0; r < 4; r++) bia[r] = ((const float*)(smem + OFF_B3))[orow + r];
        const int i0 = lg * 8;
        for (int idx = 0; idx < 12; ++idx) {
            const int s = idx / 3, t0 = (idx % 3) * 16;
            const char* base = smem + OFF_C2 + s * S2B;
            f32x4 acc = {0.f, 0.f, 0.f, 0.f};
            #pragma unroll
            for (int kk = 0; kk < 5; kk++) {
                int row = 2 * t0 + 2 * lr + kk + 2;
                bf16x8 bf = ld_frag8(base + row * (C2_CH * 2) + i0 * 2);
                acc = __builtin_amdgcn_mfma_f32_16x16x32_bf16(af[kk], bf, acc, 0, 0, 0);
            }
            const int tw = t0 + lr;
            if (tw < L3n) {
                short4v pk = { f2b(fmaxf(acc[0] + bia[0], 0.f)), f2b(fmaxf(acc[1] + bia[1], 0.f)),
                               f2b(fmaxf(acc[2] + bia[2], 0.f)), f2b(fmaxf(acc[3] + bia[3], 0.f)) };
                int byteoff = (tw * 64 + orow) * 2;
                byteoff ^= (tw & 7) << 4;
                *(short4v*)(smem + OFF_C1 + s * S3B + byteoff) = pk;
            }
        }
    }
    __syncthreads();

    // ---------------- P4: fc via MFMA (M rows = samples, N=64, K=2880) ----------------
    {
        const int j0 = wv * 16;
        const int sA = lr & 3;                 // clamp: rows 4..15 duplicate 0..3, discarded
        f32x4 acc0 = {0.f, 0.f, 0.f, 0.f}, acc1 = {0.f, 0.f, 0.f, 0.f};
        const short* fcwb = ws ? (const short*)(ws + WSO_FCW) : nullptr;
        for (int kt = 0; kt < 90; kt += 2) {
            {
                int k = kt * 32 + lg * 8;
                int bo = (k * 2) ^ (((k >> 6) & 7) << 4);
                bf16x8 av = *(const bf16x8*)(smem + OFF_C1 + sA * S3B + bo);
                bf16x8 bv;
                if (fcwb) bv = *(const bf16x8*)(fcwb + (long)(j0 + lr) * FCIN + k);
                else {
                    #pragma unroll
                    for (int e = 0; e < 8; e++) {
                        int mp = k + e, o = mp & 63, t = mp >> 6;
                        bv[e] = f2b(fcw[(long)(j0 + lr) * FCIN + o * 45 + t]);
                    }
                }
                acc0 = __builtin_amdgcn_mfma_f32_16x16x32_bf16(av, bv, acc0, 0, 0, 0);
            }
            {
                int k = (kt + 1) * 32 + lg * 8;
                int bo = (k * 2) ^ (((k >> 6) & 7) << 4);
                bf16x8 av = *(const bf16x8*)(smem + OFF_C1 + sA * S3B + bo);
                bf16x8 bv;
                if (fcwb) bv = *(const bf16x8*)(fcwb + (long)(j0 + lr) * FCIN + k);
                else {
                    #pragma unroll
                    for (int e = 0; e < 8; e++) {
                        int mp = k + e, o = mp & 63, t = mp >> 6;
                        bv[e] = f2b(fcw[(long)(j0 + lr) * FCIN + o * 45 + t]);
                    }
                }
                acc1 = __builtin_amdgcn_mfma_f32_16x16x32_bf16(av, bv, acc1, 0, 0, 0);
            }
        }
        if (lg == 0) {
            float* st = (float*)(smem + OFF_STATE);
            float fb = ((const float*)(smem + OFF_FCB))[j0 + lr];
            #pragma unroll
            for (int r = 0; r < 4; r++)
                st[r * 68 + j0 + lr] = acc0[r] + acc1[r] + fb;
        }
        if (tid < NS * 3) {
            int s = tid / 3, jj = tid % 3;
            ((float*)(smem + OFF_STATE))[s * 68 + 64 + jj] = odom[((long)blockIdx.x * NS + s) * 3 + jj];
        }
    }
    __syncthreads();

    // ---------------- P5: SINDy tail fp32 (one wave / sample) ----------------
    {
        const float* st = (const float*)(smem + OFF_STATE) + wv * 68;
        const unsigned short* qab = ws ? (const unsigned short*)(ws + WSO_QAB) : nullptr;
        const long n = (long)blockIdx.x * NS + wv;
        float a0 = 0.f, a1 = 0.f, a2 = 0.f;
        for (int i = lane; i < SD; i += 64) {
            float sv = st[i], sn = sinf(sv), cs = cosf(sv);
            a0 += sw[1 + i] * sv + sw[2346 + i] * sn + sw[2413 + i] * cs;
            a1 += sw[LIB + 1 + i] * sv + sw[LIB + 2346 + i] * sn + sw[LIB + 2413 + i] * cs;
            a2 += sw[2 * LIB + 1 + i] * sv + sw[2 * LIB + 2346 + i] * sn + sw[2 * LIB + 2413 + i] * cs;
        }
        if (lane == 0) { a0 += sw[0]; a1 += sw[LIB]; a2 += sw[2 * LIB]; }
        for (int q = lane; q < NQ; q += 64) {
            int a, b;
            if (qab) { int ab = qab[q]; a = ab >> 8; b = ab & 255; }
            else { int2 ab = qab_of(q); a = ab.x; b = ab.y; }
            float p = st[a] * st[b];
            a0 += sw[68 + q] * p; a1 += sw[LIB + 68 + q] * p; a2 += sw[2 * LIB + 68 + q] * p;
        }
        #pragma unroll
        for (int off = 32; off; off >>= 1) {
            a0 += __shfl_xor(a0, off, 64);
            a1 += __shfl_xor(a1, off, 64);
            a2 += __shfl_xor(a2, off, 64);
        }
        if (lane == 0) {
            out[n * 3 + 0] = odom[n * 3 + 0] + 0.1f * a0;
            out[n * 3 + 1] = odom[n * 3 + 1] + 0.1f * a1;
            out[n * 3 + 2] = odom[n * 3 + 2] + 0.1f * a2;
        }
    }
}

extern "C" void kernel_launch(void* const* d_in, const int* in_sizes, int n_in,
                              void* d_out, int out_size, void* d_ws, size_t ws_size,
                              hipStream_t stream) {
    const float* lidar = (const float*)d_in[0];
    const float* odom  = (const float*)d_in[1];
    const float* w1    = (const float*)d_in[2];
    const float* b1    = (const float*)d_in[3];
    const float* w2    = (const float*)d_in[4];
    const float* b2    = (const float*)d_in[5];
    const float* w3    = (const float*)d_in[6];
    const float* b3    = (const float*)d_in[7];
    const float* fcw   = (const float*)d_in[8];
    const float* fcb   = (const float*)d_in[9];
    const float* sw    = (const float*)d_in[10];
    float* out = (float*)d_out;

    int B = in_sizes[0] / L0;          // 32768
    int blocks = B / NS;               // 8192

    char* ws = nullptr;
    if (ws_size >= WS_NEED) {
        ws = (char*)d_ws;
        pre_convert<<<(64 * FCIN + 255) / 256, 256, 0, stream>>>(fcw, w2, w3, ws);
    }
    sindy_mfma<<<blocks, NT, 0, stream>>>(lidar, odom, w1, b1, w2, b2, w3, b3,
                                          fcw, fcb, sw, ws, out);
}

// Round 4
// 301.274 us; speedup vs baseline: 14.3724x; 2.2285x over previous
//
#include <hip/hip_runtime.h>
#include <hip/hip_bf16.h>

typedef __attribute__((ext_vector_type(8))) short bf16x8;
typedef __attribute__((ext_vector_type(4))) short short4v;
typedef __attribute__((ext_vector_type(4))) float f32x4;
typedef __attribute__((ext_vector_type(4))) float float4v;

#define NT 1024
#define NS 16
#define NSG 4
#define NGRP 4

constexpr int L0 = 360, L2n = 90, L3n = 45;
constexpr int SD = 67, NQ = 2278, LIB = 2480, FCIN = 2880;

constexpr int C1_CH = 20, C1_ROWS = 186, S1B = C1_ROWS * C1_CH * 2;  // 7440
constexpr int C2_CH = 44, C2_ROWS = 96, S2B = C2_ROWS * C2_CH * 2;   // 8448
constexpr int S3B = 5776;   // per-sample c3 stride (16B aligned, stride/4 mod 32 = 4 -> 2-way)

constexpr int OFF_C3 = 0;
constexpr int SZ_C3 = NS * S3B;             // 92416
constexpr int OFF_C1 = OFF_C3 + SZ_C3;      // 92416
constexpr int SZ_C1 = NSG * S1B;            // 29760
constexpr int OFF_C2 = OFF_C1 + SZ_C1;      // 122176
constexpr int SZ_C2 = NSG * S2B + 512;      // 34304 (pad for tail garbage reads)
constexpr int OFF_LID = OFF_C2 + SZ_C2;     // 156480
constexpr int SZ_LID = NSG * L0 * 4;        // 5760
constexpr int OFF_PAR = OFF_LID + SZ_LID;   // 162240 ; f32: w1[80] b1[16] b2[32] b3[64] fcb[64]
constexpr int SMEM_BYTES = OFF_PAR + 1024;  // 163264
static_assert(SMEM_BYTES <= 163840, "LDS over budget");

constexpr int OFF_STATE = OFF_C1;           // [16][68] f32, aliases c1 (dead by fc-reduce)
constexpr int OFF_FCRED = OFF_C2;           // [4][4][16][17] f32, aliases c2 (dead after conv3 g3)

// workspace layout (bytes)
constexpr size_t WSO_FCW = 0;                          // [64][2880] bf16, m'=t*64+o
constexpr size_t WSO_W2F = WSO_FCW + 64 * FCIN * 2;    // [3][32][32] bf16
constexpr size_t WSO_W3F = WSO_W2F + 3 * 32 * 32 * 2;  // [5][64][32] bf16
constexpr size_t WSO_QAB = WSO_W3F + 5 * 64 * 32 * 2;  // [2278] u16
constexpr size_t WS_NEED = WSO_QAB + NQ * 2;

__device__ __forceinline__ short f2b(float f) {
    return (short)__builtin_bit_cast(unsigned short, __float2bfloat16(f));
}
__device__ __forceinline__ bf16x8 ld_frag8(const char* p) {   // 8B-aligned LDS, 2x ds_read_b64
    union { bf16x8 v; short4v h[2]; } u;
    u.h[0] = *(const short4v*)(p);
    u.h[1] = *(const short4v*)(p + 8);
    return u.v;
}
__device__ __forceinline__ int2 qab_of(int q) {
    float qf = (float)q;
    int a = (int)((135.0f - sqrtf(135.0f * 135.0f - 8.0f * qf)) * 0.5f);
    a = a < 0 ? 0 : (a > 66 ? 66 : a);
    while (a > 0 && (a * 67 - (a * (a - 1)) / 2) > q) --a;
    while (a < 66 && ((a + 1) * 67 - ((a + 1) * a) / 2) <= q) ++a;
    int b = a + (q - (a * 67 - (a * (a - 1)) / 2));
    return make_int2(a, b);
}

__global__ __launch_bounds__(256) void pre_convert(
    const float* __restrict__ fcw, const float* __restrict__ w2,
    const float* __restrict__ w3, char* __restrict__ ws) {
    int idx = blockIdx.x * 256 + threadIdx.x;
    if (idx < 64 * FCIN) {
        int j = idx / FCIN, mp = idx % FCIN;
        int o = mp & 63, t = mp >> 6;
        ((short*)(ws + WSO_FCW))[idx] = f2b(fcw[j * FCIN + o * 45 + t]);
    }
    if (idx < 3 * 32 * 32) {
        int p = idx >> 10, o = (idx >> 5) & 31, k32 = idx & 31;
        int kk = 2 * p + (k32 >> 4), ic = k32 & 15;
        float v = (kk < 5) ? w2[(o * 16 + ic) * 5 + kk] : 0.f;
        ((short*)(ws + WSO_W2F))[idx] = f2b(v);
    }
    if (idx < 5 * 64 * 32) {
        int kk = idx >> 11, o = (idx >> 5) & 63, ic = idx & 31;
        ((short*)(ws + WSO_W3F))[idx] = f2b(w3[(o * 32 + ic) * 5 + kk]);
    }
    if (idx < NQ) {
        int2 ab = qab_of(idx);
        ((unsigned short*)(ws + WSO_QAB))[idx] = (unsigned short)((ab.x << 8) | ab.y);
    }
}

__global__ __launch_bounds__(NT, 4) void sindy_mfma(
    const float* __restrict__ lidar, const float* __restrict__ odom,
    const float* __restrict__ w1, const float* __restrict__ b1,
    const float* __restrict__ w2, const float* __restrict__ b2,
    const float* __restrict__ w3, const float* __restrict__ b3,
    const float* __restrict__ fcw, const float* __restrict__ fcb,
    const float* __restrict__ sw, const char* __restrict__ ws,
    float* __restrict__ out)
{
    __shared__ char smem[SMEM_BYTES];
    const int tid = threadIdx.x;
    const int wv = tid >> 6, lane = tid & 63;
    const int lr = lane & 15, lg = lane >> 4;
    const long blk = blockIdx.x;
    float* par = (float*)(smem + OFF_PAR);

    // ================= P0: params + border zero + lidar g0 =================
    if (tid < 80) par[tid] = w1[tid];
    else if (tid >= 128 && tid < 144) par[80 + tid - 128] = b1[tid - 128];
    else if (tid >= 192 && tid < 224) par[96 + tid - 192] = b2[tid - 192];
    else if (tid >= 256 && tid < 320) par[128 + tid - 256] = b3[tid - 256];
    else if (tid >= 384 && tid < 448) par[192 + tid - 384] = fcb[tid - 384];
    if (tid >= 448 && tid < 608) {              // c1 borders: 4 slots * rows{2,3,184,185} * 10 ints
        int i = tid - 448;                      // 0..159
        int slot = i / 40, r = i % 40;
        const int rows[4] = {2, 3, 184, 185};
        int row = rows[r / 10], c = r % 10;
        *(int*)(smem + OFF_C1 + slot * S1B + row * (C1_CH * 2) + c * 4) = 0;
    }
    if (tid >= 608 && tid < 960) {              // c2 borders: 4 slots * rows{2,3,94,95} * 22 ints
        int i = tid - 608;                      // 0..351
        int slot = i / 88, r = i % 88;
        const int rows[4] = {2, 3, 94, 95};
        int row = rows[r / 22], c = r % 22;
        *(int*)(smem + OFF_C2 + slot * S2B + row * (C2_CH * 2) + c * 4) = 0;
    }
    if (tid < 360)                               // lidar group 0
        ((float4v*)(smem + OFF_LID))[tid] = ((const float4v*)(lidar + blk * NS * L0))[tid];
    __syncthreads();

    // ================= conv groups =================
    for (int g = 0; g < NGRP; ++g) {
        // ---- C1: conv1 fp32 VALU, 4 waves per sample ----
        {
            const int s = wv & 3, quad = wv >> 2;
            const int op = lane >> 3, o0 = op * 2;
            const int slot = quad * 8 + (lane & 7);         // 0..31
            float wA[5], wB[5];
            #pragma unroll
            for (int k = 0; k < 5; k++) { wA[k] = par[o0 * 5 + k]; wB[k] = par[o0 * 5 + 5 + k]; }
            float bA = par[80 + o0], bB = par[80 + o0 + 1];
            const float* xs = (const float*)(smem + OFF_LID) + s * L0;
            char* c1s = smem + OFF_C1 + s * S1B;
            #pragma unroll
            for (int j = 0; j < 6; ++j) {
                int t = slot + 32 * j;
                if (t < 180) {
                    float a0 = bA, a1 = bB;
                    #pragma unroll
                    for (int k = 0; k < 5; k++) {
                        int u = 2 * t + k - 2;
                        float x = (u >= 0 && u < L0) ? xs[u] : 0.f;
                        a0 += wA[k] * x; a1 += wB[k] * x;
                    }
                    a0 = fmaxf(a0, 0.f); a1 = fmaxf(a1, 0.f);
                    int pk = (int)(unsigned short)f2b(a0) | ((int)(unsigned short)f2b(a1) << 16);
                    *(int*)(c1s + (t + 4) * (C1_CH * 2) + o0 * 2) = pk;
                }
            }
        }
        __syncthreads();

        // ---- C2: conv2 MFMA (+ stage lidar g+1) ----
        {
            const int s = wv & 3, q = wv >> 2;
            const int ot = q >> 1, o0 = ot * 16;
            bf16x8 af[3];
            if (ws) {
                #pragma unroll
                for (int p = 0; p < 3; p++)
                    af[p] = *(const bf16x8*)(ws + WSO_W2F + ((p * 32 + o0 + lr) * 32 + lg * 8) * 2);
            } else {
                #pragma unroll
                for (int p = 0; p < 3; p++)
                    #pragma unroll
                    for (int e = 0; e < 8; e++) {
                        int k32 = lg * 8 + e, kk = 2 * p + (k32 >> 4), ic = k32 & 15;
                        af[p][e] = (kk < 5) ? f2b(w2[((o0 + lr) * 16 + ic) * 5 + kk]) : (short)0;
                    }
            }
            const int orow = o0 + lg * 4;
            float bia[4];
            #pragma unroll
            for (int r = 0; r < 4; r++) bia[r] = par[96 + orow + r];
            const int kkp = lane >> 5, i0 = (lg & 1) * 8;
            const char* base = smem + OFF_C1 + s * S1B;
            char* c2s = smem + OFF_C2 + s * S2B;
            float4v lv;
            const bool stg = (g < NGRP - 1) && (tid < 360);
            if (stg) lv = ((const float4v*)(lidar + (blk * NS + (g + 1) * NSG) * L0))[tid];
            #pragma unroll
            for (int i = 0; i < 3; ++i) {
                const int t0 = ((q & 1) * 3 + i) * 16;
                f32x4 acc = {0.f, 0.f, 0.f, 0.f};
                #pragma unroll
                for (int p = 0; p < 3; p++) {
                    int row = 2 * t0 + 2 * lr + 2 * p + kkp + 2;
                    bf16x8 bf = ld_frag8(base + row * (C1_CH * 2) + i0 * 2);
                    acc = __builtin_amdgcn_mfma_f32_16x16x32_bf16(af[p], bf, acc, 0, 0, 0);
                }
                const int tw = t0 + lr;
                if (tw < L2n) {
                    short4v pk = { f2b(fmaxf(acc[0] + bia[0], 0.f)), f2b(fmaxf(acc[1] + bia[1], 0.f)),
                                   f2b(fmaxf(acc[2] + bia[2], 0.f)), f2b(fmaxf(acc[3] + bia[3], 0.f)) };
                    *(short4v*)(c2s + (tw + 4) * (C2_CH * 2) + orow * 2) = pk;
                }
            }
            if (stg) ((float4v*)(smem + OFF_LID))[tid] = lv;
        }
        __syncthreads();

        // ---- C3: conv3 MFMA -> c3 (swizzled) ----
        {
            const int s = wv & 3, ot = wv >> 2, o0 = ot * 16;
            bf16x8 af[5];
            if (ws) {
                #pragma unroll
                for (int kk = 0; kk < 5; kk++)
                    af[kk] = *(const bf16x8*)(ws + WSO_W3F + ((kk * 64 + o0 + lr) * 32 + lg * 8) * 2);
            } else {
                #pragma unroll
                for (int kk = 0; kk < 5; kk++)
                    #pragma unroll
                    for (int e = 0; e < 8; e++)
                        af[kk][e] = f2b(w3[((o0 + lr) * 32 + lg * 8 + e) * 5 + kk]);
            }
            const int orow = o0 + lg * 4;
            float bia[4];
            #pragma unroll
            for (int r = 0; r < 4; r++) bia[r] = par[128 + orow + r];
            const int i0 = lg * 8;
            const char* base = smem + OFF_C2 + s * S2B;
            char* c3s = smem + OFF_C3 + (g * NSG + s) * S3B;
            #pragma unroll
            for (int tt = 0; tt < 3; ++tt) {
                const int t0 = tt * 16;
                f32x4 acc = {0.f, 0.f, 0.f, 0.f};
                #pragma unroll
                for (int kk = 0; kk < 5; kk++) {
                    int row = 2 * t0 + 2 * lr + kk + 2;
                    bf16x8 bf = ld_frag8(base + row * (C2_CH * 2) + i0 * 2);
                    acc = __builtin_amdgcn_mfma_f32_16x16x32_bf16(af[kk], bf, acc, 0, 0, 0);
                }
                const int tw = t0 + lr;
                if (tw < L3n) {
                    short4v pk = { f2b(fmaxf(acc[0] + bia[0], 0.f)), f2b(fmaxf(acc[1] + bia[1], 0.f)),
                                   f2b(fmaxf(acc[2] + bia[2], 0.f)), f2b(fmaxf(acc[3] + bia[3], 0.f)) };
                    int byteoff = (tw * 64 + orow) * 2;
                    byteoff ^= (tw & 7) << 4;
                    *(short4v*)(c3s + byteoff) = pk;
                }
            }
        }
        __syncthreads();
    }

    // ================= FC: M=16, N=64, K=2880 ; wave = (j-tile, k-quarter) =================
    {
        const int jt = wv & 3, kq = wv >> 2, j0 = jt * 16;
        const int nI = (kq < 2) ? 23 : 22;
        f32x4 acc = {0.f, 0.f, 0.f, 0.f};
        const short* fb = ws ? (const short*)(ws + WSO_FCW) + (long)(j0 + lr) * FCIN : nullptr;
        auto loadB = [&](int kt) -> bf16x8 {
            int k = kt * 32 + lg * 8;
            if (fb) return *(const bf16x8*)(fb + k);
            bf16x8 bv;
            #pragma unroll
            for (int e = 0; e < 8; e++) {
                int mp = k + e, o = mp & 63, t = mp >> 6;
                bv[e] = f2b(fcw[(long)(j0 + lr) * FCIN + o * 45 + t]);
            }
            return bv;
        };
        int kt = kq;
        bf16x8 bv = loadB(kt);
        for (int i = 0; i < nI; ++i) {
            bf16x8 bvn = bv;
            if (i + 1 < nI) bvn = loadB(kt + 4);
            int k = kt * 32 + lg * 8;
            int bo = (k * 2) ^ (((k >> 6) & 7) << 4);
            bf16x8 av = *(const bf16x8*)(smem + OFF_C3 + lr * S3B + bo);
            acc = __builtin_amdgcn_mfma_f32_16x16x32_bf16(av, bv, acc, 0, 0, 0);
            bv = bvn; kt += 4;
        }
        float* red = (float*)(smem + OFF_FCRED);
        #pragma unroll
        for (int r = 0; r < 4; r++)
            red[((jt * 4 + kq) * 16 + lg * 4 + r) * 17 + lr] = acc[r];
    }
    __syncthreads();
    {   // reduce 4 k-quarters -> state
        float* red = (float*)(smem + OFF_FCRED);
        float* stt = (float*)(smem + OFF_STATE);
        if (wv < 4) {
            const int jt = wv, j0 = jt * 16;
            #pragma unroll
            for (int e = 0; e < 4; e++) {
                int idx = e * 64 + lane, row = idx >> 4, col = idx & 15;
                float s_ = red[((jt * 4 + 0) * 16 + row) * 17 + col]
                         + red[((jt * 4 + 1) * 16 + row) * 17 + col]
                         + red[((jt * 4 + 2) * 16 + row) * 17 + col]
                         + red[((jt * 4 + 3) * 16 + row) * 17 + col];
                stt[row * 68 + j0 + col] = s_ + par[192 + j0 + col];
            }
        }
        if (tid < NS * 3) {
            int s = tid / 3, jj = tid % 3;
            stt[s * 68 + 64 + jj] = odom[(blk * NS + s) * 3 + jj];
        }
    }
    __syncthreads();

    // ================= SINDy tail: wave = sample =================
    {
        const float* st = (const float*)(smem + OFF_STATE) + wv * 68;
        const unsigned short* qab = ws ? (const unsigned short*)(ws + WSO_QAB) : nullptr;
        const long n = blk * NS + wv;
        float a0 = 0.f, a1 = 0.f, a2 = 0.f;
        for (int i = lane; i < SD; i += 64) {
            float sv = st[i], sn = sinf(sv), cs = cosf(sv);
            a0 += sw[1 + i] * sv + sw[2346 + i] * sn + sw[2413 + i] * cs;
            a1 += sw[LIB + 1 + i] * sv + sw[LIB + 2346 + i] * sn + sw[LIB + 2413 + i] * cs;
            a2 += sw[2 * LIB + 1 + i] * sv + sw[2 * LIB + 2346 + i] * sn + sw[2 * LIB + 2413 + i] * cs;
        }
        if (lane == 0) { a0 += sw[0]; a1 += sw[LIB]; a2 += sw[2 * LIB]; }
        // NQ loop, 1-deep prefetch of LUT + 3 weight streams
        int q = lane;
        bool v = q < NQ;
        int abn = 0; float w0n = 0.f, w1n = 0.f, w2n = 0.f;
        if (v) {
            abn = qab ? (int)qab[q] : ((qab_of(q).x << 8) | qab_of(q).y);
            w0n = sw[68 + q]; w1n = sw[LIB + 68 + q]; w2n = sw[2 * LIB + 68 + q];
        }
        while (v) {
            int ab = abn; float wq0 = w0n, wq1 = w1n, wq2 = w2n;
            int qn = q + 64;
            bool vn = qn < NQ;
            if (vn) {
                abn = qab ? (int)qab[qn] : ((qab_of(qn).x << 8) | qab_of(qn).y);
                w0n = sw[68 + qn]; w1n = sw[LIB + 68 + qn]; w2n = sw[2 * LIB + 68 + qn];
            }
            float p = st[ab >> 8] * st[ab & 255];
            a0 += wq0 * p; a1 += wq1 * p; a2 += wq2 * p;
            q = qn; v = vn;
        }
        #pragma unroll
        for (int off = 32; off; off >>= 1) {
            a0 += __shfl_xor(a0, off, 64);
            a1 += __shfl_xor(a1, off, 64);
            a2 += __shfl_xor(a2, off, 64);
        }
        if (lane == 0) {
            out[n * 3 + 0] = odom[n * 3 + 0] + 0.1f * a0;
            out[n * 3 + 1] = odom[n * 3 + 1] + 0.1f * a1;
            out[n * 3 + 2] = odom[n * 3 + 2] + 0.1f * a2;
        }
    }
}

extern "C" void kernel_launch(void* const* d_in, const int* in_sizes, int n_in,
                              void* d_out, int out_size, void* d_ws, size_t ws_size,
                              hipStream_t stream) {
    const float* lidar = (const float*)d_in[0];
    const float* odom  = (const float*)d_in[1];
    const float* w1    = (const float*)d_in[2];
    const float* b1    = (const float*)d_in[3];
    const float* w2    = (const float*)d_in[4];
    const float* b2    = (const float*)d_in[5];
    const float* w3    = (const float*)d_in[6];
    const float* b3    = (const float*)d_in[7];
    const float* fcw   = (const float*)d_in[8];
    const float* fcb   = (const float*)d_in[9];
    const float* sw    = (const float*)d_in[10];
    float* out = (float*)d_out;

    int B = in_sizes[0] / L0;          // 32768
    int blocks = B / NS;               // 2048

    char* ws = nullptr;
    if (ws_size >= WS_NEED) {
        ws = (char*)d_ws;
        pre_convert<<<(64 * FCIN + 255) / 256, 256, 0, stream>>>(fcw, w2, w3, ws);
    }
    sindy_mfma<<<blocks, NT, 0, stream>>>(lidar, odom, w1, b1, w2, b2, w3, b3,
                                          fcw, fcb, sw, ws, out);
}